// Round 22
// baseline (299.753 us; speedup 1.0000x reference)
//
#include <hip/hip_runtime.h>
#include <math.h>

// Problem constants (fixed by setup_inputs)
#define B_    8
#define T_    8192
#define LIN   1536
#define D_    768
#define H_    8
#define E_    96
#define TT    16            // tokens per tile (24KB LDS)
#define BPB   (T_ / TT)     // 512 tiles per batch
#define NBLK  1024          // kF grid; each block pipelines NITER tiles
#define NITER 4             // NBLK * NITER == B_*T_/TT == 4096

typedef float f32x4 __attribute__((ext_vector_type(4)));
typedef short s16x8 __attribute__((ext_vector_type(8)));

static __device__ __forceinline__ short f2bf(float f) {   // RNE f32 -> bf16 bits
    unsigned u = __float_as_uint(f);
    unsigned r = (u + 0x7FFFu + ((u >> 16) & 1u)) >> 16;
    return (short)r;
}
static __device__ __forceinline__ float bf2f(short s) {
    return __uint_as_float(((unsigned)(unsigned short)s) << 16);
}
// tanh(a)*sigmoid(g) = (1-e^-2a) / ((1+e^-2a)(1+e^-g)) with single v_rcp_f32.
static __device__ __forceinline__ float fused_gate(float a, float g) {
    float ta = __expf(-2.0f * a);
    float tg = __expf(-g);
    return (1.0f - ta) * __builtin_amdgcn_rcpf((1.0f + ta) * (1.0f + tg));
}
// LDS-only barrier: waits own LDS ops, does NOT drain vmcnt (keeps the
// cross-tile register prefetch in flight; plain __syncthreads would emit
// s_waitcnt vmcnt(0) and kill the pipeline). Every use protects only
// LDS write->read; loads in flight target registers (no cross-thread
// visibility needed), global stores are consumed only by later kernels.
static __device__ __forceinline__ void lds_barrier() {
    asm volatile("s_waitcnt lgkmcnt(0)" ::: "memory");
    __builtin_amdgcn_s_barrier();
    asm volatile("" ::: "memory");
}

// ---------------------------------------------------------------------------
// Kernel 0: weight prep. Wa,Wb [h][e][f] f32 -> wtA,wtB [h][f][e] bf16.
// ---------------------------------------------------------------------------
__global__ __launch_bounds__(256)
void k0_wprep(const float* __restrict__ Wa, const float* __restrict__ Wb,
              short* __restrict__ wtA, short* __restrict__ wtB)
{
    int o = blockIdx.x * 256 + threadIdx.x;
    if (o >= H_ * E_ * E_) return;
    int e = o % E_;
    int f = (o / E_) % E_;
    int h = o / (E_ * E_);
    int in = h * E_ * E_ + e * E_ + f;
    wtA[o] = f2bf(Wa[in]);
    wtB[o] = f2bf(Wb[in]);
}

// ---------------------------------------------------------------------------
// Kernel F (fused, cross-tile software pipeline). Each block processes NITER
// tiles; tile i+1's 24 dwordx4 x-loads are issued before tile i's stage-2
// barrier and consumed a full tile later, so HBM streaming overlaps the
// compute phases (breaks the phase convoy R19-R21 diagnosed). All math
// bit-identical to R18 (passed, 175.2us).
// ---------------------------------------------------------------------------
__global__ __launch_bounds__(256)
void kF_fused(const float* __restrict__ x,
              const float* __restrict__ gamma, const float* __restrict__ beta,
              const short* __restrict__ wtA, const short* __restrict__ wtB,
              const float* __restrict__ ba, const float* __restrict__ bb,
              const float* __restrict__ Wc, const float* __restrict__ bc,
              float* __restrict__ partial, float* __restrict__ mzb)
{
    __shared__ __align__(16) short xnt[TT * D_];   // 24 KB bf16 tile
    __shared__ float red2[TT][4];
    __shared__ float scs[TT];
    __shared__ float wsh[TT];

    const int tid  = threadIdx.x;
    const int lane = tid & 63;
    const int wv   = tid >> 6;

    // ---- hoisted per-lane constants (R18 phase-A expressions) ----
    const float SCALE = (float)(1535.0 / 767.0);
    float gm[12], btv[12], wl[12];
    int   dst0[12];
    #pragma unroll
    for (int c = 0; c < 3; ++c)
        #pragma unroll
        for (int d = 0; d < 4; ++d) {
            int k = 4 * c + d;
            int j = 256 * c + 4 * lane + d;
            float pos = (float)j * SCALE;
            int a = (int)floorf(pos);
            if (a > LIN - 1) a = LIN - 1;
            wl[k] = pos - (float)a;
            gm[k]  = gamma[j];
            btv[k] = beta[j];
            dst0[k] = (j & 7) * E_ + (j >> 3);   // head-major position
        }
    const bool last = (lane == 63);
    const int ln15 = lane & 15;
    const int q    = lane >> 4;

    // ---- prologue: prefetch tile 0 (4 tokens/wave x 6 f32x4) ----
    f32x4 P[4][6];
    {
        const float* base = x + ((size_t)blockIdx.x * TT + wv * 4) * LIN;
        #pragma unroll
        for (int tt = 0; tt < 4; ++tt) {
            const float* r = base + (size_t)tt * LIN;
            #pragma unroll
            for (int c = 0; c < 3; ++c) {
                P[tt][2 * c]     = *(const f32x4*)&r[512 * c + 8 * lane];
                P[tt][2 * c + 1] = *(const f32x4*)&r[512 * c + 8 * lane + 4];
            }
        }
    }

    #pragma unroll 1
    for (int it = 0; it < NITER; ++it) {
        const int bid = blockIdx.x + it * NBLK;
        const int bt0 = bid * TT;

        // ---- Phase A: resize + LN from P (R18 math verbatim) ----
        #pragma unroll
        for (int tt = 0; tt < 4; ++tt) {
            float xr[12];
            float sum = 0.0f, ssq = 0.0f;
            #pragma unroll
            for (int c = 0; c < 3; ++c) {
                f32x4 A  = P[tt][2 * c];
                f32x4 Bv = P[tt][2 * c + 1];
                #pragma unroll
                for (int d = 0; d < 4; ++d) {
                    int k = 4 * c + d;
                    int idx = (d & 1) * 2;
                    float lo = (d < 2) ? A[idx]     : Bv[idx];
                    float hi = (d < 2) ? A[idx + 1] : Bv[idx + 1];
                    if (c == 2 && d == 3 && last && wl[k] == 0.0f)
                        lo = P[tt][5][3];          // j=767 clamp
                    float v = lo * (1.0f - wl[k]) + hi * wl[k];
                    xr[k] = v; sum += v; ssq = fmaf(v, v, ssq);
                }
            }

            #pragma unroll
            for (int o = 1; o < 64; o <<= 1) {
                sum += __shfl_xor(sum, o, 64);
                ssq += __shfl_xor(ssq, o, 64);
            }
            float mu = sum * (1.0f / D_);
            float rs = 1.0f / sqrtf(ssq * (1.0f / D_) - mu * mu + 1e-5f);

            const int tok = wv * 4 + tt;
            const int swz = (tok & 7) << 3;
            #pragma unroll
            for (int k = 0; k < 12; ++k) {
                int sidx = (tok * D_ + dst0[k]) ^ swz;
                xnt[sidx] = f2bf((xr[k] - mu) * rs * gm[k] + btv[k]);
            }
        }

        // ---- issue next tile's loads (in flight across stages 2-4) ----
        if (it + 1 < NITER) {
            const float* nb = x + ((size_t)(bid + NBLK) * TT + wv * 4) * LIN;
            #pragma unroll
            for (int tt = 0; tt < 4; ++tt) {
                const float* r = nb + (size_t)tt * LIN;
                #pragma unroll
                for (int c = 0; c < 3; ++c) {
                    P[tt][2 * c]     = *(const f32x4*)&r[512 * c + 8 * lane];
                    P[tt][2 * c + 1] = *(const f32x4*)&r[512 * c + 8 * lane + 4];
                }
            }
        }

        lds_barrier();   // xnt ready; prefetch NOT drained

        // ---- Stage 2: MFMA scoring (R18 verbatim) ----
        const int tokA = ln15;
        const int swzA = (tokA & 7) << 3;

        float hacc[4] = {0.0f, 0.0f, 0.0f, 0.0f};

        #pragma unroll
        for (int hh = 0; hh < 2; ++hh) {
            const int h = wv * 2 + hh;
            s16x8 afr[3];
            #pragma unroll
            for (int kk = 0; kk < 3; ++kk) {
                int sidx = (tokA * D_ + h * E_ + kk * 32 + q * 8) ^ swzA;
                afr[kk] = *(const s16x8*)&xnt[sidx];
            }
            f32x4 accA[6], accG[6];
            #pragma unroll
            for (int nt = 0; nt < 6; ++nt) {
                accA[nt] = (f32x4){0.f, 0.f, 0.f, 0.f};
                accG[nt] = (f32x4){0.f, 0.f, 0.f, 0.f};
            }
            #pragma unroll
            for (int nt = 0; nt < 6; ++nt) {
                const short* rowA = wtA + h * (E_ * E_) + (nt * 16 + ln15) * E_ + q * 8;
                const short* rowB = wtB + h * (E_ * E_) + (nt * 16 + ln15) * E_ + q * 8;
                #pragma unroll
                for (int kk = 0; kk < 3; ++kk) {
                    s16x8 bA = *(const s16x8*)(rowA + kk * 32);
                    s16x8 bG = *(const s16x8*)(rowB + kk * 32);
                    accA[nt] = __builtin_amdgcn_mfma_f32_16x16x32_bf16(afr[kk], bA, accA[nt], 0, 0, 0);
                    accG[nt] = __builtin_amdgcn_mfma_f32_16x16x32_bf16(afr[kk], bG, accG[nt], 0, 0, 0);
                }
            }
            float v0 = 0.f, v1 = 0.f, v2 = 0.f, v3 = 0.f;
            #pragma unroll
            for (int nt = 0; nt < 6; ++nt) {
                int f = nt * 16 + ln15;
                float bav = ba[h * E_ + f];
                float bbv = bb[h * E_ + f];
                float wcv = Wc[h * E_ + f];
                v0 += fused_gate(accA[nt][0] + bav, accG[nt][0] + bbv) * wcv;
                v1 += fused_gate(accA[nt][1] + bav, accG[nt][1] + bbv) * wcv;
                v2 += fused_gate(accA[nt][2] + bav, accG[nt][2] + bbv) * wcv;
                v3 += fused_gate(accA[nt][3] + bav, accG[nt][3] + bbv) * wcv;
            }
            hacc[0] += v0; hacc[1] += v1; hacc[2] += v2; hacc[3] += v3;
        }

        #pragma unroll
        for (int r = 0; r < 4; ++r) {
            float v = hacc[r];
            v += __shfl_xor(v, 1, 64);
            v += __shfl_xor(v, 2, 64);
            v += __shfl_xor(v, 4, 64);
            v += __shfl_xor(v, 8, 64);
            hacc[r] = v;
        }
        if (ln15 == 0) {
            #pragma unroll
            for (int r = 0; r < 4; ++r)
                red2[q * 4 + r][wv] = hacc[r];
        }
        lds_barrier();

        // ---- Stage 3: final scores for the 16 tokens ----
        if (tid < TT) {
            float bcsum = 0.0f;
            #pragma unroll
            for (int h2 = 0; h2 < H_; ++h2) bcsum += bc[h2];
            scs[tid] = (red2[tid][0] + red2[tid][1] + red2[tid][2] + red2[tid][3]
                        + bcsum) * (1.0f / H_);
        }
        lds_barrier();

        // ---- Stage 4: block-local softmax weights + pool from LDS ----
        float mb = scs[0];
        #pragma unroll
        for (int t = 1; t < TT; ++t) mb = fmaxf(mb, scs[t]);
        if (tid < TT) wsh[tid] = __expf(scs[tid] - mb);
        lds_barrier();

        if (tid == 0) {
            float zb = 0.0f;
            #pragma unroll
            for (int t = 0; t < TT; ++t) zb += wsh[t];
            mzb[bid * 2]     = mb;
            mzb[bid * 2 + 1] = zb;
        }

        float wt[TT];
        #pragma unroll
        for (int t = 0; t < TT; ++t) wt[t] = wsh[t];

        float* pp = partial + (size_t)bid * D_;
        #pragma unroll
        for (int kk = 0; kk < 3; ++kk) {
            int jp = kk * 256 + tid;   // head-major feature index j' = h*96+e
            float a = 0.0f;
            #pragma unroll
            for (int t = 0; t < TT; ++t)
                a = fmaf(wt[t], bf2f(xnt[(t * D_ + jp) ^ ((t & 7) << 3)]), a);
            pp[jp] = a;
        }

        lds_barrier();   // xnt consumption done; safe to overwrite next iter
    }
}

// ---------------------------------------------------------------------------
// Kernel 4 (includes M/Z combine): per (batch, third), reduce 512 block
// (m,z) -> (M, 1/Z), build scales in LDS, combine partials -> out[b, 768]
// (permute j' = h*96+e -> j = e*8+h). Verbatim R18 (passed).
// ---------------------------------------------------------------------------
__global__ __launch_bounds__(256)
void k4_reduce(const float* __restrict__ partial, const float* __restrict__ mzb,
               float* __restrict__ out)
{
    __shared__ float red[8];
    __shared__ float Msh, Zsh;
    __shared__ float sc[BPB];
    const int b = blockIdx.x / 3, third = blockIdx.x % 3, tid = threadIdx.x;
    const int lane = tid & 63, wv = tid >> 6;

    const float* pm = mzb + (size_t)b * BPB * 2;
    float m0 = pm[tid * 2], m1 = pm[(tid + 256) * 2];
    float z0 = pm[tid * 2 + 1], z1 = pm[(tid + 256) * 2 + 1];

    float M = fmaxf(m0, m1);
    #pragma unroll
    for (int o = 32; o > 0; o >>= 1) M = fmaxf(M, __shfl_down(M, o, 64));
    if (lane == 0) red[wv] = M;
    __syncthreads();
    if (tid == 0) Msh = fmaxf(fmaxf(red[0], red[1]), fmaxf(red[2], red[3]));
    __syncthreads();
    M = Msh;

    float e0 = __expf(m0 - M), e1 = __expf(m1 - M);
    float Z = z0 * e0 + z1 * e1;
    #pragma unroll
    for (int o = 32; o > 0; o >>= 1) Z += __shfl_down(Z, o, 64);
    if (lane == 0) red[wv] = Z;
    __syncthreads();
    if (tid == 0) Zsh = 1.0f / (red[0] + red[1] + red[2] + red[3]);
    __syncthreads();
    const float Zinv = Zsh;

    sc[tid]       = e0 * Zinv;
    sc[tid + 256] = e1 * Zinv;
    __syncthreads();

    const int jp = third * 256 + tid;
    const float* pp = partial + (size_t)b * BPB * D_ + jp;
    float sum = 0.0f;
    for (int c = 0; c < BPB; ++c)
        sum = fmaf(pp[(size_t)c * D_], sc[c], sum);

    int h = jp / 96, e = jp % 96;
    out[b * D_ + e * 8 + h] = sum;
}

// ---------------------------------------------------------------------------
extern "C" void kernel_launch(void* const* d_in, const int* in_sizes, int n_in,
                              void* d_out, int out_size, void* d_ws, size_t ws_size,
                              hipStream_t stream)
{
    const float* x     = (const float*)d_in[0];
    // d_in[1] = lens (unused: uniform == L_IN, reference ignores it)
    const float* gamma = (const float*)d_in[2];
    const float* beta  = (const float*)d_in[3];
    const float* Wa    = (const float*)d_in[4];
    const float* ba    = (const float*)d_in[5];
    const float* Wb    = (const float*)d_in[6];
    const float* bb    = (const float*)d_in[7];
    const float* Wc    = (const float*)d_in[8];
    const float* bc    = (const float*)d_in[9];
    float* out = (float*)d_out;

    float* ws      = (float*)d_ws;
    float* partial = ws;                                   // B*512*768 f32 (12.6 MB)
    float* mzb     = partial + (size_t)B_ * BPB * D_;      // B*512*2 f32 (32 KB)
    short* wtA     = (short*)(mzb + (size_t)B_ * BPB * 2); // H*E*E bf16
    short* wtB     = wtA + H_ * E_ * E_;

    hipLaunchKernelGGL(k0_wprep, dim3((H_ * E_ * E_ + 255) / 256), dim3(256), 0, stream,
                       Wa, Wb, wtA, wtB);
    hipLaunchKernelGGL(kF_fused, dim3(NBLK), dim3(256), 0, stream,
                       x, gamma, beta, wtA, wtB, ba, bb, Wc, bc, partial, mzb);
    hipLaunchKernelGGL(k4_reduce, dim3(B_ * 3), dim3(256), 0, stream,
                       partial, mzb, out);
}

// Round 23
// 174.278 us; speedup vs baseline: 1.7200x; 1.7200x over previous
//
#include <hip/hip_runtime.h>
#include <math.h>

// Problem constants (fixed by setup_inputs)
#define B_    8
#define T_    8192
#define LIN   1536
#define D_    768
#define H_    8
#define E_    96
#define TT    16            // tokens per block in kF (24KB LDS)
#define BPB   (T_ / TT)     // 512 kF-blocks per batch

typedef float f32x4 __attribute__((ext_vector_type(4)));
typedef short s16x8 __attribute__((ext_vector_type(8)));
typedef short s16x4 __attribute__((ext_vector_type(4)));

static __device__ __forceinline__ short f2bf(float f) {   // RNE f32 -> bf16 bits
    unsigned u = __float_as_uint(f);
    unsigned r = (u + 0x7FFFu + ((u >> 16) & 1u)) >> 16;
    return (short)r;
}
static __device__ __forceinline__ float bf2f(short s) {
    return __uint_as_float(((unsigned)(unsigned short)s) << 16);
}
// tanh(a)*sigmoid(g) = (1-e^-2a) / ((1+e^-2a)(1+e^-g)) with single v_rcp_f32.
static __device__ __forceinline__ float fused_gate(float a, float g) {
    float ta = __expf(-2.0f * a);
    float tg = __expf(-g);
    return (1.0f - ta) * __builtin_amdgcn_rcpf((1.0f + ta) * (1.0f + tg));
}

// ---------------------------------------------------------------------------
// Kernel 0: weight prep. Wa,Wb [h][e][f] f32 -> wtA,wtB [h][f][e] bf16.
// ---------------------------------------------------------------------------
__global__ __launch_bounds__(256)
void k0_wprep(const float* __restrict__ Wa, const float* __restrict__ Wb,
              short* __restrict__ wtA, short* __restrict__ wtB)
{
    int o = blockIdx.x * 256 + threadIdx.x;
    if (o >= H_ * E_ * E_) return;
    int e = o % E_;
    int f = (o / E_) % E_;
    int h = o / (E_ * E_);
    int in = h * E_ * E_ + e * E_ + f;
    wtA[o] = f2bf(Wa[in]);
    wtB[o] = f2bf(Wb[in]);
}

// ---------------------------------------------------------------------------
// Kernel F (fused; R18 verbatim — best verified build, 175.2us):
//   Phase A: resize+LN from x (4 tokens/wave, 1-ahead prefetch) -> bf16
//            head-major XOR-swizzled LDS tile.
//   Stage 2: MFMA scoring (2 heads/wave) + fused_gate activations.
//   Stage 3: final scores. Stage 4: block online-softmax partial pooling.
// ---------------------------------------------------------------------------
__global__ __launch_bounds__(256)
void kF_fused(const float* __restrict__ x,
              const float* __restrict__ gamma, const float* __restrict__ beta,
              const short* __restrict__ wtA, const short* __restrict__ wtB,
              const float* __restrict__ ba, const float* __restrict__ bb,
              const float* __restrict__ Wc, const float* __restrict__ bc,
              float* __restrict__ partial, float* __restrict__ mzb)
{
    __shared__ __align__(16) short xnt[TT * D_];   // 24 KB bf16 tile
    __shared__ float red2[TT][4];
    __shared__ float scs[TT];
    __shared__ float wsh[TT];

    const int bid  = blockIdx.x;
    const int tid  = threadIdx.x;
    const int lane = tid & 63;
    const int wv   = tid >> 6;
    const int bt0  = bid * TT;

    // ---- Phase A: resize + LN for this wave's 4 tokens ----
    {
        const float SCALE = (float)(1535.0 / 767.0);
        float gm[12], btv[12], wl[12];
        int   dst0[12];
        #pragma unroll
        for (int c = 0; c < 3; ++c)
            #pragma unroll
            for (int d = 0; d < 4; ++d) {
                int k = 4 * c + d;
                int j = 256 * c + 4 * lane + d;
                float pos = (float)j * SCALE;
                int a = (int)floorf(pos);
                if (a > LIN - 1) a = LIN - 1;
                wl[k] = pos - (float)a;
                gm[k]  = gamma[j];
                btv[k] = beta[j];
                dst0[k] = (j & 7) * E_ + (j >> 3);   // head-major position
            }
        const bool last = (lane == 63);

        const int t0 = wv * 4;                        // wave's tokens in tile
        const float* base = x + (size_t)(bt0 + t0) * LIN;

        f32x4 La0 = *(const f32x4*)&base[           8 * lane];
        f32x4 Lb0 = *(const f32x4*)&base[           8 * lane + 4];
        f32x4 La1 = *(const f32x4*)&base[512  +     8 * lane];
        f32x4 Lb1 = *(const f32x4*)&base[512  +     8 * lane + 4];
        f32x4 La2 = *(const f32x4*)&base[1024 +     8 * lane];
        f32x4 Lb2 = *(const f32x4*)&base[1024 +     8 * lane + 4];

        #pragma unroll
        for (int tt = 0; tt < 4; ++tt) {
            f32x4 Na0, Nb0, Na1, Nb1, Na2, Nb2;
            if (tt < 3) {
                const float* nr = base + (size_t)(tt + 1) * LIN;
                Na0 = *(const f32x4*)&nr[           8 * lane];
                Nb0 = *(const f32x4*)&nr[           8 * lane + 4];
                Na1 = *(const f32x4*)&nr[512  +     8 * lane];
                Nb1 = *(const f32x4*)&nr[512  +     8 * lane + 4];
                Na2 = *(const f32x4*)&nr[1024 +     8 * lane];
                Nb2 = *(const f32x4*)&nr[1024 +     8 * lane + 4];
            }

            float xr[12];
            float sum = 0.0f, ssq = 0.0f;
            #pragma unroll
            for (int c = 0; c < 3; ++c) {
                f32x4 A  = (c == 0) ? La0 : (c == 1) ? La1 : La2;
                f32x4 Bv = (c == 0) ? Lb0 : (c == 1) ? Lb1 : Lb2;
                #pragma unroll
                for (int d = 0; d < 4; ++d) {
                    int k = 4 * c + d;
                    int idx = (d & 1) * 2;
                    float lo = (d < 2) ? A[idx]     : Bv[idx];
                    float hi = (d < 2) ? A[idx + 1] : Bv[idx + 1];
                    if (c == 2 && d == 3 && last && wl[k] == 0.0f)
                        lo = Lb2[3];               // j=767 clamp
                    float v = lo * (1.0f - wl[k]) + hi * wl[k];
                    xr[k] = v; sum += v; ssq = fmaf(v, v, ssq);
                }
            }

            #pragma unroll
            for (int o = 1; o < 64; o <<= 1) {
                sum += __shfl_xor(sum, o, 64);
                ssq += __shfl_xor(ssq, o, 64);
            }
            float mu = sum * (1.0f / D_);
            float rs = 1.0f / sqrtf(ssq * (1.0f / D_) - mu * mu + 1e-5f);

            const int tok = t0 + tt;
            const int swz = (tok & 7) << 3;
            #pragma unroll
            for (int k = 0; k < 12; ++k) {
                int sidx = (tok * D_ + dst0[k]) ^ swz;
                xnt[sidx] = f2bf((xr[k] - mu) * rs * gm[k] + btv[k]);
            }

            if (tt < 3) {
                La0 = Na0; Lb0 = Nb0; La1 = Na1; Lb1 = Nb1; La2 = Na2; Lb2 = Nb2;
            }
        }
    }
    __syncthreads();

    // ---- Stage 2: MFMA scoring ----
    const int ln15 = lane & 15;
    const int q    = lane >> 4;
    const int tokA = ln15;
    const int swzA = (tokA & 7) << 3;

    float hacc[4] = {0.0f, 0.0f, 0.0f, 0.0f};

    #pragma unroll
    for (int hh = 0; hh < 2; ++hh) {
        const int h = wv * 2 + hh;
        s16x8 afr[3];
        #pragma unroll
        for (int kk = 0; kk < 3; ++kk) {
            int sidx = (tokA * D_ + h * E_ + kk * 32 + q * 8) ^ swzA;
            afr[kk] = *(const s16x8*)&xnt[sidx];
        }
        f32x4 accA[6], accG[6];
        #pragma unroll
        for (int nt = 0; nt < 6; ++nt) {
            accA[nt] = (f32x4){0.f, 0.f, 0.f, 0.f};
            accG[nt] = (f32x4){0.f, 0.f, 0.f, 0.f};
        }
        #pragma unroll
        for (int nt = 0; nt < 6; ++nt) {
            const short* rowA = wtA + h * (E_ * E_) + (nt * 16 + ln15) * E_ + q * 8;
            const short* rowB = wtB + h * (E_ * E_) + (nt * 16 + ln15) * E_ + q * 8;
            #pragma unroll
            for (int kk = 0; kk < 3; ++kk) {
                s16x8 bA = *(const s16x8*)(rowA + kk * 32);
                s16x8 bG = *(const s16x8*)(rowB + kk * 32);
                accA[nt] = __builtin_amdgcn_mfma_f32_16x16x32_bf16(afr[kk], bA, accA[nt], 0, 0, 0);
                accG[nt] = __builtin_amdgcn_mfma_f32_16x16x32_bf16(afr[kk], bG, accG[nt], 0, 0, 0);
            }
        }
        float v0 = 0.f, v1 = 0.f, v2 = 0.f, v3 = 0.f;
        #pragma unroll
        for (int nt = 0; nt < 6; ++nt) {
            int f = nt * 16 + ln15;
            float bav = ba[h * E_ + f];
            float bbv = bb[h * E_ + f];
            float wcv = Wc[h * E_ + f];
            v0 += fused_gate(accA[nt][0] + bav, accG[nt][0] + bbv) * wcv;
            v1 += fused_gate(accA[nt][1] + bav, accG[nt][1] + bbv) * wcv;
            v2 += fused_gate(accA[nt][2] + bav, accG[nt][2] + bbv) * wcv;
            v3 += fused_gate(accA[nt][3] + bav, accG[nt][3] + bbv) * wcv;
        }
        hacc[0] += v0; hacc[1] += v1; hacc[2] += v2; hacc[3] += v3;
    }

    #pragma unroll
    for (int r = 0; r < 4; ++r) {
        float v = hacc[r];
        v += __shfl_xor(v, 1, 64);
        v += __shfl_xor(v, 2, 64);
        v += __shfl_xor(v, 4, 64);
        v += __shfl_xor(v, 8, 64);
        hacc[r] = v;
    }
    if (ln15 == 0) {
        #pragma unroll
        for (int r = 0; r < 4; ++r)
            red2[q * 4 + r][wv] = hacc[r];
    }
    __syncthreads();

    // ---- Stage 3: final scores for the 16 tokens ----
    if (tid < TT) {
        float bcsum = 0.0f;
        #pragma unroll
        for (int h2 = 0; h2 < H_; ++h2) bcsum += bc[h2];
        scs[tid] = (red2[tid][0] + red2[tid][1] + red2[tid][2] + red2[tid][3]
                    + bcsum) * (1.0f / H_);
    }
    __syncthreads();

    // ---- Stage 4: block-local softmax weights (LDS-shared) + pool ----
    float mb = scs[0];
    #pragma unroll
    for (int t = 1; t < TT; ++t) mb = fmaxf(mb, scs[t]);
    if (tid < TT) wsh[tid] = __expf(scs[tid] - mb);
    __syncthreads();

    if (tid == 0) {
        float zb = 0.0f;
        #pragma unroll
        for (int t = 0; t < TT; ++t) zb += wsh[t];
        mzb[bid * 2]     = mb;
        mzb[bid * 2 + 1] = zb;
    }

    float wt[TT];
    #pragma unroll
    for (int t = 0; t < TT; ++t) wt[t] = wsh[t];

    float* pp = partial + (size_t)bid * D_;
    #pragma unroll
    for (int kk = 0; kk < 3; ++kk) {
        int jp = kk * 256 + tid;   // head-major feature index j' = h*96+e
        float a = 0.0f;
        #pragma unroll
        for (int t = 0; t < TT; ++t)
            a = fmaf(wt[t], bf2f(xnt[(t * D_ + jp) ^ ((t & 7) << 3)]), a);
        pp[jp] = a;
    }
}

// ---------------------------------------------------------------------------
// Kernel 4 (includes M/Z combine): per (batch, third), reduce 512 block
// (m,z) -> (M, 1/Z), build scales in LDS, combine partials -> out[b, 768]
// (permute j' = h*96+e -> j = e*8+h). Verbatim R18 (passed).
// ---------------------------------------------------------------------------
__global__ __launch_bounds__(256)
void k4_reduce(const float* __restrict__ partial, const float* __restrict__ mzb,
               float* __restrict__ out)
{
    __shared__ float red[8];
    __shared__ float Msh, Zsh;
    __shared__ float sc[BPB];
    const int b = blockIdx.x / 3, third = blockIdx.x % 3, tid = threadIdx.x;
    const int lane = tid & 63, wv = tid >> 6;

    const float* pm = mzb + (size_t)b * BPB * 2;
    float m0 = pm[tid * 2], m1 = pm[(tid + 256) * 2];
    float z0 = pm[tid * 2 + 1], z1 = pm[(tid + 256) * 2 + 1];

    float M = fmaxf(m0, m1);
    #pragma unroll
    for (int o = 32; o > 0; o >>= 1) M = fmaxf(M, __shfl_down(M, o, 64));
    if (lane == 0) red[wv] = M;
    __syncthreads();
    if (tid == 0) Msh = fmaxf(fmaxf(red[0], red[1]), fmaxf(red[2], red[3]));
    __syncthreads();
    M = Msh;

    float e0 = __expf(m0 - M), e1 = __expf(m1 - M);
    float Z = z0 * e0 + z1 * e1;
    #pragma unroll
    for (int o = 32; o > 0; o >>= 1) Z += __shfl_down(Z, o, 64);
    if (lane == 0) red[wv] = Z;
    __syncthreads();
    if (tid == 0) Zsh = 1.0f / (red[0] + red[1] + red[2] + red[3]);
    __syncthreads();
    const float Zinv = Zsh;

    sc[tid]       = e0 * Zinv;
    sc[tid + 256] = e1 * Zinv;
    __syncthreads();

    const int jp = third * 256 + tid;
    const float* pp = partial + (size_t)b * BPB * D_ + jp;
    float sum = 0.0f;
    for (int c = 0; c < BPB; ++c)
        sum = fmaf(pp[(size_t)c * D_], sc[c], sum);

    int h = jp / 96, e = jp % 96;
    out[b * D_ + e * 8 + h] = sum;
}

// ---------------------------------------------------------------------------
extern "C" void kernel_launch(void* const* d_in, const int* in_sizes, int n_in,
                              void* d_out, int out_size, void* d_ws, size_t ws_size,
                              hipStream_t stream)
{
    const float* x     = (const float*)d_in[0];
    // d_in[1] = lens (unused: uniform == L_IN, reference ignores it)
    const float* gamma = (const float*)d_in[2];
    const float* beta  = (const float*)d_in[3];
    const float* Wa    = (const float*)d_in[4];
    const float* ba    = (const float*)d_in[5];
    const float* Wb    = (const float*)d_in[6];
    const float* bb    = (const float*)d_in[7];
    const float* Wc    = (const float*)d_in[8];
    const float* bc    = (const float*)d_in[9];
    float* out = (float*)d_out;

    float* ws      = (float*)d_ws;
    float* partial = ws;                                   // B*512*768 f32 (12.6 MB)
    float* mzb     = partial + (size_t)B_ * BPB * D_;      // B*512*2 f32 (32 KB)
    short* wtA     = (short*)(mzb + (size_t)B_ * BPB * 2); // H*E*E bf16
    short* wtB     = wtA + H_ * E_ * E_;

    hipLaunchKernelGGL(k0_wprep, dim3((H_ * E_ * E_ + 255) / 256), dim3(256), 0, stream,
                       Wa, Wb, wtA, wtB);
    hipLaunchKernelGGL(kF_fused, dim3(B_ * T_ / TT), dim3(256), 0, stream,
                       x, gamma, beta, wtA, wtB, ba, bb, Wc, bc, partial, mzb);
    hipLaunchKernelGGL(k4_reduce, dim3(B_ * 3), dim3(256), 0, stream,
                       partial, mzb, out);
}